// Round 11
// baseline (420.223 us; speedup 1.0000x reference)
//
#include <hip/hip_runtime.h>
#include <hip/hip_fp16.h>
#include <math.h>

#define DDIM    128
#define KCODES  256
#define NTOKS   (8 * 65536)   // 524288 tokens
#define TAUKEY  62914         // 0.03 * 8192 * 256
#define CTAU    0.01f

typedef float f32x4 __attribute__((ext_vector_type(4)));
typedef _Float16 half8 __attribute__((ext_vector_type(8)));

#define MFMAH(a, b, c) __builtin_amdgcn_mfma_f32_16x16x32_f16(a, b, c, 0, 0, 0)

union H8 { uint4 u; half8 h; };

__device__ __forceinline__ half8 pk4(float a0, float a1, float a2, float a3,
                                     float b0, float b1, float b2, float b3) {
    H8 r;
    r.u.x = __builtin_bit_cast(unsigned, __builtin_amdgcn_cvt_pkrtz(a0, a1));
    r.u.y = __builtin_bit_cast(unsigned, __builtin_amdgcn_cvt_pkrtz(a2, a3));
    r.u.z = __builtin_bit_cast(unsigned, __builtin_amdgcn_cvt_pkrtz(b0, b1));
    r.u.w = __builtin_bit_cast(unsigned, __builtin_amdgcn_cvt_pkrtz(b2, b3));
    return r.h;
}

// A-split: hi = RTZ(f32) [packed], lo captures the remainder (incl. RTZ bias)
__device__ __forceinline__ void split8(const float4& A, const float4& B,
                                       half8& hi, half8& lo) {
    hi = pk4(A.x, A.y, A.z, A.w, B.x, B.y, B.z, B.w);
    lo = pk4(A.x - (float)hi[0], A.y - (float)hi[1],
             A.z - (float)hi[2], A.w - (float)hi[3],
             B.x - (float)hi[4], B.y - (float)hi[5],
             B.z - (float)hi[6], B.w - (float)hi[7]);
}

// ROUND-11: r10 (r0 + setprio, 395.6us total — the proven best) + WAVE-PHASE
// STAGGER. Mechanism: same-SIMD waves run the unrolled phases in near-lockstep —
// both issue MFMA clusters together (pipe contention; why setprio paid +12%) and
// both sit in the dependent scoreboard VALU together (MFMA pipe idle). Offsetting
// each wave's cg scan start by ((w>>2)<<3) puts the two waves sharing a SIMD
// (w and w+4, round-robin w&3 mapping) 8-of-16 cgs apart: one wave's MFMA cluster
// overlaps the other's scoreboard by construction. Scan order is correctness-free
// (min over unique keys); zero register-pressure risk (one add+mask per cg).
__global__ __launch_bounds__(512, 2) void rvq_screen20(
    const float* __restrict__ x, const float* __restrict__ cb,
    float* __restrict__ out, unsigned* __restrict__ ws, unsigned wcap)
{
    __shared__ __align__(16) _Float16 chs[2 * KCODES * DDIM];  // 128KB, swizzled
    __shared__ float kc2[2 * KCODES];                          // 8192*||c||^2
    __shared__ int   bidx[8][2][32];

    const int tid   = threadIdx.x;
    const int w     = tid >> 6;
    const int lane  = tid & 63;
    const int lquad = lane >> 4;
    const int l15   = lane & 15;
    const int cgoff = (w >> 2) << 3;   // 0 for waves 0-3, 8 for waves 4-7

    // ---- stage BOTH layers once: RNE f16 + 8192*c2; 4 phases, no inner barriers ----
    #pragma unroll
    for (int ph = 0; ph < 4; ++ph) {
        const int row = ph * 128 + (tid >> 2);   // 0..511 = layer*256 + code
        const int sq  = tid & 3;
        const int code = row & 255;
        const float* src = cb + (size_t)row * DDIM + sq * 32;
        float c2p = 0.f;
        #pragma unroll
        for (int s = 0; s < 4; ++s) {
            const float4 a = ((const float4*)src)[s * 2 + 0];
            const float4 b = ((const float4*)src)[s * 2 + 1];
            half8 hh;                                   // RNE scalar converts
            hh[0] = (_Float16)a.x; hh[1] = (_Float16)a.y;
            hh[2] = (_Float16)a.z; hh[3] = (_Float16)a.w;
            hh[4] = (_Float16)b.x; hh[5] = (_Float16)b.y;
            hh[6] = (_Float16)b.z; hh[7] = (_Float16)b.w;
            c2p = fmaf(a.x, a.x, c2p); c2p = fmaf(a.y, a.y, c2p);
            c2p = fmaf(a.z, a.z, c2p); c2p = fmaf(a.w, a.w, c2p);
            c2p = fmaf(b.x, b.x, c2p); c2p = fmaf(b.y, b.y, c2p);
            c2p = fmaf(b.z, b.z, c2p); c2p = fmaf(b.w, b.w, c2p);
            const unsigned c = (unsigned)(sq * 4 + s);   // 16B chunk 0..15
            const unsigned off = ((unsigned)(row >> 8) << 16) + (unsigned)code * 256u +
                                 ((c ^ ((unsigned)code & 15u)) << 4);
            *(half8*)((char*)chs + off) = hh;
        }
        c2p += __shfl_xor(c2p, 1);
        c2p += __shfl_xor(c2p, 2);
        if (sq == 0) kc2[row] = c2p * 8192.0f;
    }
    __syncthreads();   // the ONLY barrier

    // ---- stream 8 tiles of 32 tokens per wave; no further syncs ----
    #pragma unroll 1
    for (int t = 0; t < 8; ++t) {
        const size_t base = (size_t)blockIdx.x * 2048 + (size_t)t * 256 + (size_t)w * 32;

        // x rows kept in registers (also used for the layer-1 rebuild)
        float4 xr[2][4][2];
        half8 ah[2][4], al[2][4];
        #pragma unroll
        for (int mt = 0; mt < 2; ++mt) {
            const float* xp = x + (base + (size_t)(mt * 16 + l15)) * DDIM;
            #pragma unroll
            for (int kst = 0; kst < 4; ++kst) {
                xr[mt][kst][0] = *(const float4*)(xp + kst * 32 + lquad * 8);
                xr[mt][kst][1] = *(const float4*)(xp + kst * 32 + lquad * 8 + 4);
                split8(xr[mt][kst][0], xr[mt][kst][1], ah[mt][kst], al[mt][kst]);
            }
        }

        #pragma unroll
        for (int l = 0; l < 2; ++l) {
            int b1[2][4], b2[2][4];
            #pragma unroll
            for (int mt = 0; mt < 2; ++mt)
                #pragma unroll
                for (int rg = 0; rg < 4; ++rg) { b1[mt][rg] = 0x7FFFFFFF; b2[mt][rg] = 0x7FFFFFFF; }

            #pragma unroll
            for (int cgi = 0; cgi < 16; ++cgi) {
                const int cg = (cgi + cgoff) & 15;   // wave-phase stagger
                f32x4 acc0 = (f32x4){0.f, 0.f, 0.f, 0.f};
                f32x4 acc1 = (f32x4){0.f, 0.f, 0.f, 0.f};
                const unsigned codeL = (unsigned)(cg * 16 + l15);
                __builtin_amdgcn_s_setprio(1);   // T5: favor this wave's MFMA cluster
                #pragma unroll
                for (int kst = 0; kst < 4; ++kst) {
                    const unsigned off = ((unsigned)l << 16) + codeL * 256u +
                        ((((unsigned)(kst * 4 + lquad)) ^ (codeL & 15u)) << 4);
                    const half8 bh = *(half8*)((char*)chs + off);
                    acc0 = MFMAH(ah[0][kst], bh, acc0);
                    acc0 = MFMAH(al[0][kst], bh, acc0);
                    acc1 = MFMAH(ah[1][kst], bh, acc1);
                    acc1 = MFMAH(al[1][kst], bh, acc1);
                }
                __builtin_amdgcn_s_setprio(0);
                const int codeg = cg * 16 + l15;
                const float kc = kc2[l * KCODES + codeg];
                #pragma unroll
                for (int mt = 0; mt < 2; ++mt) {
                    const f32x4& acc = mt ? acc1 : acc0;
                    #pragma unroll
                    for (int rg = 0; rg < 4; ++rg) {
                        const float dk = fmaf(-16384.f, acc[rg], kc);
                        const int key = ((int)dk << 8) + codeg;   // (dist, code) lexicographic
                        const int mx = (b1[mt][rg] > key) ? b1[mt][rg] : key;
                        b1[mt][rg] = (b1[mt][rg] < key) ? b1[mt][rg] : key;
                        b2[mt][rg] = (b2[mt][rg] < mx) ? b2[mt][rg] : mx;
                    }
                }
            }

            // cross-lane reduce over 16 l15-lanes (unique keys -> no tie handling)
            #pragma unroll
            for (int m = 1; m <= 8; m <<= 1) {
                #pragma unroll
                for (int mt = 0; mt < 2; ++mt)
                    #pragma unroll
                    for (int rg = 0; rg < 4; ++rg) {
                        const int ob1 = __shfl_xor(b1[mt][rg], m);
                        const int ob2 = __shfl_xor(b2[mt][rg], m);
                        const int mx = (b1[mt][rg] > ob1) ? b1[mt][rg] : ob1;
                        const int mn2 = (b2[mt][rg] < ob2) ? b2[mt][rg] : ob2;
                        b1[mt][rg] = (b1[mt][rg] < ob1) ? b1[mt][rg] : ob1;
                        b2[mt][rg] = (mn2 < mx) ? mn2 : mx;
                    }
            }

            // flush indices + flags (per-wave bidx: same-wave LDS write->read, no barrier)
            if (l15 == 0) {
                #pragma unroll
                for (int mt = 0; mt < 2; ++mt)
                    #pragma unroll
                    for (int rg = 0; rg < 4; ++rg) {
                        const int trel = mt * 16 + lquad * 4 + rg;
                        const int code = b1[mt][rg] & 0xFF;
                        bidx[w][l][trel] = code;
                        out[(size_t)NTOKS * DDIM + (size_t)l * NTOKS + base + trel] = (float)code;
                        if ((long long)b2[mt][rg] - (long long)b1[mt][rg] < (long long)TAUKEY) {
                            const unsigned p = atomicAdd(ws, 1u);
                            if (p < wcap) ws[8 + p] = (unsigned)(base + trel);
                        }
                    }
            }

            // rebuild A for layer 1 directly from x regs: r1 = x - c0
            if (l == 0) {
                #pragma unroll
                for (int mt = 0; mt < 2; ++mt) {
                    const int b0 = bidx[w][0][mt * 16 + l15];
                    const float* c0p = cb + (size_t)b0 * DDIM;
                    #pragma unroll
                    for (int kst = 0; kst < 4; ++kst) {
                        const float4 ca = *(const float4*)(c0p + kst * 32 + lquad * 8);
                        const float4 cbv = *(const float4*)(c0p + kst * 32 + lquad * 8 + 4);
                        float4 d0, d1;
                        d0.x = xr[mt][kst][0].x - ca.x;
                        d0.y = xr[mt][kst][0].y - ca.y;
                        d0.z = xr[mt][kst][0].z - ca.z;
                        d0.w = xr[mt][kst][0].w - ca.w;
                        d1.x = xr[mt][kst][1].x - cbv.x;
                        d1.y = xr[mt][kst][1].y - cbv.y;
                        d1.z = xr[mt][kst][1].z - cbv.z;
                        d1.w = xr[mt][kst][1].w - cbv.w;
                        split8(d0, d1, ah[mt][kst], al[mt][kst]);
                    }
                }
            }
        }

        // epilogue: out = c0 + c1 (exact fp32 rows)
        #pragma unroll
        for (int mt = 0; mt < 2; ++mt) {
            const int trel = mt * 16 + l15;
            const int b0e = bidx[w][0][trel];
            const int b1e = bidx[w][1][trel];
            const float* p0 = cb + (size_t)b0e * DDIM;
            const float* p1 = cb + ((size_t)KCODES + b1e) * DDIM;
            float* op = out + (base + (size_t)trel) * DDIM;
            #pragma unroll
            for (int kst = 0; kst < 4; ++kst) {
                const float4 a0 = *(const float4*)(p0 + kst * 32 + lquad * 8);
                const float4 a1 = *(const float4*)(p0 + kst * 32 + lquad * 8 + 4);
                const float4 z0 = *(const float4*)(p1 + kst * 32 + lquad * 8);
                const float4 z1 = *(const float4*)(p1 + kst * 32 + lquad * 8 + 4);
                const float4 o0 = {a0.x + z0.x, a0.y + z0.y, a0.z + z0.z, a0.w + z0.w};
                const float4 o1 = {a1.x + z1.x, a1.y + z1.y, a1.z + z1.z, a1.w + z1.w};
                *(float4*)(op + kst * 32 + lquad * 8)     = o0;
                *(float4*)(op + kst * 32 + lquad * 8 + 4) = o1;
            }
        }
    }
}

// ---------------- Kernel 2: wave-per-token full fp64 rescue (proven rounds 5-9) ----------------
__global__ __launch_bounds__(256, 4) void rvq_rescue2(
    const float* __restrict__ x, const float* __restrict__ cb,
    float* __restrict__ out, const unsigned* __restrict__ ws, unsigned wcap)
{
    __shared__ float rshF[4][DDIM];
    const int tid = threadIdx.x, lane = tid & 63, w = tid >> 6;

    unsigned cnt = ws[0]; if (cnt > wcap) cnt = wcap;
    const unsigned nwaves = gridDim.x * 4;

    for (unsigned wi = blockIdx.x * 4 + w; wi < cnt; wi += nwaves) {
        const size_t tok = ws[8 + wi];
        const float* xrow = x + tok * DDIM;
        const float x0 = xrow[lane], x1 = xrow[lane + 64];
        double rd0 = (double)x0, rd1 = (double)x1;
        rshF[w][lane] = x0; rshF[w][lane + 64] = x1;

        #pragma unroll
        for (int l = 0; l < 2; ++l) {
            const float* cbl = cb + (size_t)l * KCODES * DDIM;

            float d32[4];
            #pragma unroll
            for (int cc = 0; cc < 4; ++cc) {
                const float* crow = cbl + (size_t)(lane * 4 + cc) * DDIM;
                float s0 = 0.f, s1 = 0.f, s2 = 0.f, s3 = 0.f;
                #pragma unroll 8
                for (int i = 0; i < DDIM; i += 4) {
                    const float e0 = rshF[w][i + 0] - crow[i + 0];
                    const float e1 = rshF[w][i + 1] - crow[i + 1];
                    const float e2 = rshF[w][i + 2] - crow[i + 2];
                    const float e3 = rshF[w][i + 3] - crow[i + 3];
                    s0 = fmaf(e0, e0, s0); s1 = fmaf(e1, e1, s1);
                    s2 = fmaf(e2, e2, s2); s3 = fmaf(e3, e3, s3);
                }
                d32[cc] = (s0 + s1) + (s2 + s3);
            }
            float wmin = fminf(fminf(d32[0], d32[1]), fminf(d32[2], d32[3]));
            #pragma unroll
            for (int m = 1; m < 64; m <<= 1) wmin = fminf(wmin, __shfl_xor(wmin, m));

            double bestd = 1e300; int bestc = 0x7FFFFFFF;
            #pragma unroll
            for (int cc = 0; cc < 4; ++cc) {
                unsigned long long msk = __ballot(d32[cc] <= wmin + CTAU);
                while (msk) {
                    const int ln = __ffsll((long long)msk) - 1; msk &= msk - 1;
                    const int code = ln * 4 + cc;
                    const float* crow = cbl + (size_t)code * DDIM;
                    const double e0 = rd0 - (double)crow[lane];
                    const double e1 = rd1 - (double)crow[lane + 64];
                    double v = fma(e0, e0, e1 * e1);
                    #pragma unroll
                    for (int m = 1; m < 64; m <<= 1) v += __shfl_xor(v, m);
                    if (v < bestd || (v == bestd && code < bestc)) { bestd = v; bestc = code; }
                }
            }

            const float* qrow = cbl + (size_t)bestc * DDIM;
            rd0 -= (double)qrow[lane];
            rd1 -= (double)qrow[lane + 64];
            if (l == 0) { rshF[w][lane] = (float)rd0; rshF[w][lane + 64] = (float)rd1; }
            if (lane == 0)
                out[(size_t)NTOKS * DDIM + (size_t)l * NTOKS + tok] = (float)bestc;
        }

        float* orow = out + tok * DDIM;
        orow[lane]      = (float)((double)x0 - rd0);
        orow[lane + 64] = (float)((double)x1 - rd1);
    }
}

extern "C" void kernel_launch(void* const* d_in, const int* in_sizes, int n_in,
                              void* d_out, int out_size, void* d_ws, size_t ws_size,
                              hipStream_t stream) {
    const float* x  = (const float*)d_in[0];
    const float* cb = (const float*)d_in[1];
    float* out = (float*)d_out;
    unsigned* ws = (unsigned*)d_ws;
    unsigned wcap = (ws_size >= 64) ? (unsigned)(ws_size / 4 - 16) : 0;

    hipMemsetAsync(d_ws, 0, 4, stream);
    hipLaunchKernelGGL(rvq_screen20, dim3(256), dim3(512), 0, stream,
                       x, cb, out, ws, wcap);
    hipLaunchKernelGGL(rvq_rescue2, dim3(2048), dim3(256), 0, stream,
                       x, cb, out, ws, wcap);
}

// Round 12
// 394.450 us; speedup vs baseline: 1.0653x; 1.0653x over previous
//
#include <hip/hip_runtime.h>
#include <hip/hip_fp16.h>
#include <math.h>

#define DDIM    128
#define KCODES  256
#define NTOKS   (8 * 65536)   // 524288 tokens
#define TAUKEY  62914         // 0.03 * 8192 * 256
#define CTAU    0.01f

typedef float f32x4 __attribute__((ext_vector_type(4)));
typedef _Float16 half8 __attribute__((ext_vector_type(8)));

#define MFMAH(a, b, c) __builtin_amdgcn_mfma_f32_16x16x32_f16(a, b, c, 0, 0, 0)

union H8 { uint4 u; half8 h; };

__device__ __forceinline__ half8 pk4(float a0, float a1, float a2, float a3,
                                     float b0, float b1, float b2, float b3) {
    H8 r;
    r.u.x = __builtin_bit_cast(unsigned, __builtin_amdgcn_cvt_pkrtz(a0, a1));
    r.u.y = __builtin_bit_cast(unsigned, __builtin_amdgcn_cvt_pkrtz(a2, a3));
    r.u.z = __builtin_bit_cast(unsigned, __builtin_amdgcn_cvt_pkrtz(b0, b1));
    r.u.w = __builtin_bit_cast(unsigned, __builtin_amdgcn_cvt_pkrtz(b2, b3));
    return r.h;
}

// A-split: hi = RTZ(f32) [packed], lo captures the remainder (incl. RTZ bias)
__device__ __forceinline__ void split8(const float4& A, const float4& B,
                                       half8& hi, half8& lo) {
    hi = pk4(A.x, A.y, A.z, A.w, B.x, B.y, B.z, B.w);
    lo = pk4(A.x - (float)hi[0], A.y - (float)hi[1],
             A.z - (float)hi[2], A.w - (float)hi[3],
             B.x - (float)hi[4], B.y - (float)hi[5],
             B.z - (float)hi[6], B.w - (float)hi[7]);
}

// ROUND-12: REVERT to r10 exactly (r0 + symmetric setprio; 395.6us total, the
// session best). r11's wave-phase stagger regressed -10%: (a) runtime cg broke
// compile-time LDS address folding (codeL&15==l15, so the swizzle never depended
// on cg — the masked-add bought nothing); (b) asymmetric setprio: with phases
// offset, the prio-1 wave's MFMA cluster starves the prio-0 partner's VALU issue,
// serializing the pair. In lockstep both waves raise prio together (symmetric) —
// that's the configuration that paid +12% in r10. Lever space now mapped:
// occupancy = compiler-blocked (r1-r4), restructure = spill-blocked (r5-r9),
// ILP = null (r7), arbitration = setprio-symmetric only (r10 vs r11).
__global__ __launch_bounds__(512, 2) void rvq_screen21(
    const float* __restrict__ x, const float* __restrict__ cb,
    float* __restrict__ out, unsigned* __restrict__ ws, unsigned wcap)
{
    __shared__ __align__(16) _Float16 chs[2 * KCODES * DDIM];  // 128KB, swizzled
    __shared__ float kc2[2 * KCODES];                          // 8192*||c||^2
    __shared__ int   bidx[8][2][32];

    const int tid   = threadIdx.x;
    const int w     = tid >> 6;
    const int lane  = tid & 63;
    const int lquad = lane >> 4;
    const int l15   = lane & 15;

    // ---- stage BOTH layers once: RNE f16 + 8192*c2; 4 phases, no inner barriers ----
    #pragma unroll
    for (int ph = 0; ph < 4; ++ph) {
        const int row = ph * 128 + (tid >> 2);   // 0..511 = layer*256 + code
        const int sq  = tid & 3;
        const int code = row & 255;
        const float* src = cb + (size_t)row * DDIM + sq * 32;
        float c2p = 0.f;
        #pragma unroll
        for (int s = 0; s < 4; ++s) {
            const float4 a = ((const float4*)src)[s * 2 + 0];
            const float4 b = ((const float4*)src)[s * 2 + 1];
            half8 hh;                                   // RNE scalar converts
            hh[0] = (_Float16)a.x; hh[1] = (_Float16)a.y;
            hh[2] = (_Float16)a.z; hh[3] = (_Float16)a.w;
            hh[4] = (_Float16)b.x; hh[5] = (_Float16)b.y;
            hh[6] = (_Float16)b.z; hh[7] = (_Float16)b.w;
            c2p = fmaf(a.x, a.x, c2p); c2p = fmaf(a.y, a.y, c2p);
            c2p = fmaf(a.z, a.z, c2p); c2p = fmaf(a.w, a.w, c2p);
            c2p = fmaf(b.x, b.x, c2p); c2p = fmaf(b.y, b.y, c2p);
            c2p = fmaf(b.z, b.z, c2p); c2p = fmaf(b.w, b.w, c2p);
            const unsigned c = (unsigned)(sq * 4 + s);   // 16B chunk 0..15
            const unsigned off = ((unsigned)(row >> 8) << 16) + (unsigned)code * 256u +
                                 ((c ^ ((unsigned)code & 15u)) << 4);
            *(half8*)((char*)chs + off) = hh;
        }
        c2p += __shfl_xor(c2p, 1);
        c2p += __shfl_xor(c2p, 2);
        if (sq == 0) kc2[row] = c2p * 8192.0f;
    }
    __syncthreads();   // the ONLY barrier

    // ---- stream 8 tiles of 32 tokens per wave; no further syncs ----
    #pragma unroll 1
    for (int t = 0; t < 8; ++t) {
        const size_t base = (size_t)blockIdx.x * 2048 + (size_t)t * 256 + (size_t)w * 32;

        // x rows kept in registers (also used for the layer-1 rebuild)
        float4 xr[2][4][2];
        half8 ah[2][4], al[2][4];
        #pragma unroll
        for (int mt = 0; mt < 2; ++mt) {
            const float* xp = x + (base + (size_t)(mt * 16 + l15)) * DDIM;
            #pragma unroll
            for (int kst = 0; kst < 4; ++kst) {
                xr[mt][kst][0] = *(const float4*)(xp + kst * 32 + lquad * 8);
                xr[mt][kst][1] = *(const float4*)(xp + kst * 32 + lquad * 8 + 4);
                split8(xr[mt][kst][0], xr[mt][kst][1], ah[mt][kst], al[mt][kst]);
            }
        }

        #pragma unroll
        for (int l = 0; l < 2; ++l) {
            int b1[2][4], b2[2][4];
            #pragma unroll
            for (int mt = 0; mt < 2; ++mt)
                #pragma unroll
                for (int rg = 0; rg < 4; ++rg) { b1[mt][rg] = 0x7FFFFFFF; b2[mt][rg] = 0x7FFFFFFF; }

            #pragma unroll
            for (int cg = 0; cg < 16; ++cg) {
                f32x4 acc0 = (f32x4){0.f, 0.f, 0.f, 0.f};
                f32x4 acc1 = (f32x4){0.f, 0.f, 0.f, 0.f};
                const unsigned codeL = (unsigned)(cg * 16 + l15);
                __builtin_amdgcn_s_setprio(1);   // T5: symmetric (lockstep) regime
                #pragma unroll
                for (int kst = 0; kst < 4; ++kst) {
                    const unsigned off = ((unsigned)l << 16) + codeL * 256u +
                        ((((unsigned)(kst * 4 + lquad)) ^ (codeL & 15u)) << 4);
                    const half8 bh = *(half8*)((char*)chs + off);
                    acc0 = MFMAH(ah[0][kst], bh, acc0);
                    acc0 = MFMAH(al[0][kst], bh, acc0);
                    acc1 = MFMAH(ah[1][kst], bh, acc1);
                    acc1 = MFMAH(al[1][kst], bh, acc1);
                }
                __builtin_amdgcn_s_setprio(0);
                const int codeg = cg * 16 + l15;
                const float kc = kc2[l * KCODES + codeg];
                #pragma unroll
                for (int mt = 0; mt < 2; ++mt) {
                    const f32x4& acc = mt ? acc1 : acc0;
                    #pragma unroll
                    for (int rg = 0; rg < 4; ++rg) {
                        const float dk = fmaf(-16384.f, acc[rg], kc);
                        const int key = ((int)dk << 8) + codeg;   // (dist, code) lexicographic
                        const int mx = (b1[mt][rg] > key) ? b1[mt][rg] : key;
                        b1[mt][rg] = (b1[mt][rg] < key) ? b1[mt][rg] : key;
                        b2[mt][rg] = (b2[mt][rg] < mx) ? b2[mt][rg] : mx;
                    }
                }
            }

            // cross-lane reduce over 16 l15-lanes (unique keys -> no tie handling)
            #pragma unroll
            for (int m = 1; m <= 8; m <<= 1) {
                #pragma unroll
                for (int mt = 0; mt < 2; ++mt)
                    #pragma unroll
                    for (int rg = 0; rg < 4; ++rg) {
                        const int ob1 = __shfl_xor(b1[mt][rg], m);
                        const int ob2 = __shfl_xor(b2[mt][rg], m);
                        const int mx = (b1[mt][rg] > ob1) ? b1[mt][rg] : ob1;
                        const int mn2 = (b2[mt][rg] < ob2) ? b2[mt][rg] : ob2;
                        b1[mt][rg] = (b1[mt][rg] < ob1) ? b1[mt][rg] : ob1;
                        b2[mt][rg] = (mn2 < mx) ? mn2 : mx;
                    }
            }

            // flush indices + flags (per-wave bidx: same-wave LDS write->read, no barrier)
            if (l15 == 0) {
                #pragma unroll
                for (int mt = 0; mt < 2; ++mt)
                    #pragma unroll
                    for (int rg = 0; rg < 4; ++rg) {
                        const int trel = mt * 16 + lquad * 4 + rg;
                        const int code = b1[mt][rg] & 0xFF;
                        bidx[w][l][trel] = code;
                        out[(size_t)NTOKS * DDIM + (size_t)l * NTOKS + base + trel] = (float)code;
                        if ((long long)b2[mt][rg] - (long long)b1[mt][rg] < (long long)TAUKEY) {
                            const unsigned p = atomicAdd(ws, 1u);
                            if (p < wcap) ws[8 + p] = (unsigned)(base + trel);
                        }
                    }
            }

            // rebuild A for layer 1 directly from x regs: r1 = x - c0
            if (l == 0) {
                #pragma unroll
                for (int mt = 0; mt < 2; ++mt) {
                    const int b0 = bidx[w][0][mt * 16 + l15];
                    const float* c0p = cb + (size_t)b0 * DDIM;
                    #pragma unroll
                    for (int kst = 0; kst < 4; ++kst) {
                        const float4 ca = *(const float4*)(c0p + kst * 32 + lquad * 8);
                        const float4 cbv = *(const float4*)(c0p + kst * 32 + lquad * 8 + 4);
                        float4 d0, d1;
                        d0.x = xr[mt][kst][0].x - ca.x;
                        d0.y = xr[mt][kst][0].y - ca.y;
                        d0.z = xr[mt][kst][0].z - ca.z;
                        d0.w = xr[mt][kst][0].w - ca.w;
                        d1.x = xr[mt][kst][1].x - cbv.x;
                        d1.y = xr[mt][kst][1].y - cbv.y;
                        d1.z = xr[mt][kst][1].z - cbv.z;
                        d1.w = xr[mt][kst][1].w - cbv.w;
                        split8(d0, d1, ah[mt][kst], al[mt][kst]);
                    }
                }
            }
        }

        // epilogue: out = c0 + c1 (exact fp32 rows)
        #pragma unroll
        for (int mt = 0; mt < 2; ++mt) {
            const int trel = mt * 16 + l15;
            const int b0e = bidx[w][0][trel];
            const int b1e = bidx[w][1][trel];
            const float* p0 = cb + (size_t)b0e * DDIM;
            const float* p1 = cb + ((size_t)KCODES + b1e) * DDIM;
            float* op = out + (base + (size_t)trel) * DDIM;
            #pragma unroll
            for (int kst = 0; kst < 4; ++kst) {
                const float4 a0 = *(const float4*)(p0 + kst * 32 + lquad * 8);
                const float4 a1 = *(const float4*)(p0 + kst * 32 + lquad * 8 + 4);
                const float4 z0 = *(const float4*)(p1 + kst * 32 + lquad * 8);
                const float4 z1 = *(const float4*)(p1 + kst * 32 + lquad * 8 + 4);
                const float4 o0 = {a0.x + z0.x, a0.y + z0.y, a0.z + z0.z, a0.w + z0.w};
                const float4 o1 = {a1.x + z1.x, a1.y + z1.y, a1.z + z1.z, a1.w + z1.w};
                *(float4*)(op + kst * 32 + lquad * 8)     = o0;
                *(float4*)(op + kst * 32 + lquad * 8 + 4) = o1;
            }
        }
    }
}

// ---------------- Kernel 2: wave-per-token full fp64 rescue (proven rounds 5-9) ----------------
__global__ __launch_bounds__(256, 4) void rvq_rescue2(
    const float* __restrict__ x, const float* __restrict__ cb,
    float* __restrict__ out, const unsigned* __restrict__ ws, unsigned wcap)
{
    __shared__ float rshF[4][DDIM];
    const int tid = threadIdx.x, lane = tid & 63, w = tid >> 6;

    unsigned cnt = ws[0]; if (cnt > wcap) cnt = wcap;
    const unsigned nwaves = gridDim.x * 4;

    for (unsigned wi = blockIdx.x * 4 + w; wi < cnt; wi += nwaves) {
        const size_t tok = ws[8 + wi];
        const float* xrow = x + tok * DDIM;
        const float x0 = xrow[lane], x1 = xrow[lane + 64];
        double rd0 = (double)x0, rd1 = (double)x1;
        rshF[w][lane] = x0; rshF[w][lane + 64] = x1;

        #pragma unroll
        for (int l = 0; l < 2; ++l) {
            const float* cbl = cb + (size_t)l * KCODES * DDIM;

            float d32[4];
            #pragma unroll
            for (int cc = 0; cc < 4; ++cc) {
                const float* crow = cbl + (size_t)(lane * 4 + cc) * DDIM;
                float s0 = 0.f, s1 = 0.f, s2 = 0.f, s3 = 0.f;
                #pragma unroll 8
                for (int i = 0; i < DDIM; i += 4) {
                    const float e0 = rshF[w][i + 0] - crow[i + 0];
                    const float e1 = rshF[w][i + 1] - crow[i + 1];
                    const float e2 = rshF[w][i + 2] - crow[i + 2];
                    const float e3 = rshF[w][i + 3] - crow[i + 3];
                    s0 = fmaf(e0, e0, s0); s1 = fmaf(e1, e1, s1);
                    s2 = fmaf(e2, e2, s2); s3 = fmaf(e3, e3, s3);
                }
                d32[cc] = (s0 + s1) + (s2 + s3);
            }
            float wmin = fminf(fminf(d32[0], d32[1]), fminf(d32[2], d32[3]));
            #pragma unroll
            for (int m = 1; m < 64; m <<= 1) wmin = fminf(wmin, __shfl_xor(wmin, m));

            double bestd = 1e300; int bestc = 0x7FFFFFFF;
            #pragma unroll
            for (int cc = 0; cc < 4; ++cc) {
                unsigned long long msk = __ballot(d32[cc] <= wmin + CTAU);
                while (msk) {
                    const int ln = __ffsll((long long)msk) - 1; msk &= msk - 1;
                    const int code = ln * 4 + cc;
                    const float* crow = cbl + (size_t)code * DDIM;
                    const double e0 = rd0 - (double)crow[lane];
                    const double e1 = rd1 - (double)crow[lane + 64];
                    double v = fma(e0, e0, e1 * e1);
                    #pragma unroll
                    for (int m = 1; m < 64; m <<= 1) v += __shfl_xor(v, m);
                    if (v < bestd || (v == bestd && code < bestc)) { bestd = v; bestc = code; }
                }
            }

            const float* qrow = cbl + (size_t)bestc * DDIM;
            rd0 -= (double)qrow[lane];
            rd1 -= (double)qrow[lane + 64];
            if (l == 0) { rshF[w][lane] = (float)rd0; rshF[w][lane + 64] = (float)rd1; }
            if (lane == 0)
                out[(size_t)NTOKS * DDIM + (size_t)l * NTOKS + tok] = (float)bestc;
        }

        float* orow = out + tok * DDIM;
        orow[lane]      = (float)((double)x0 - rd0);
        orow[lane + 64] = (float)((double)x1 - rd1);
    }
}

extern "C" void kernel_launch(void* const* d_in, const int* in_sizes, int n_in,
                              void* d_out, int out_size, void* d_ws, size_t ws_size,
                              hipStream_t stream) {
    const float* x  = (const float*)d_in[0];
    const float* cb = (const float*)d_in[1];
    float* out = (float*)d_out;
    unsigned* ws = (unsigned*)d_ws;
    unsigned wcap = (ws_size >= 64) ? (unsigned)(ws_size / 4 - 16) : 0;

    hipMemsetAsync(d_ws, 0, 4, stream);
    hipLaunchKernelGGL(rvq_screen21, dim3(256), dim3(512), 0, stream,
                       x, cb, out, ws, wcap);
    hipLaunchKernelGGL(rvq_rescue2, dim3(2048), dim3(256), 0, stream,
                       x, cb, out, ws, wcap);
}